// Round 9
// baseline (2619.043 us; speedup 1.0000x reference)
//
#include <hip/hip_runtime.h>
#include <hip/hip_fp16.h>

// Attention2: point-cloud attention, N=1M, KNN=9, C_in=C_inner=20, REPEAT=2.
// R4: conv1 is affine -> y[n,k] = u[idx]-v[n]; u precomputed (k0), v cheap.
// R5 FAILED: array-ref helper -> scratch (2.3 GB phantom traffic).
// R6 FAILED: cat[40] under (256,3) demoted to scratch (VGPR=84, 1.9 GB).
// R7 WIN: k6 on k0's proven shape -> 1043 us.
// R8 FAILED: compact 80-B rows -> line straddle (fetch 590->857 MB).
// R9 WIN: fp16 u in 64-B slots -> 974. FETCH floored at 9M x 64 B/gather.
// R10 WIN: fp16 xagg full-slot -> 949. 5th confirmation: gather-pass dur ==
//   TCC bytes / ~3.55-3.65 TB/s; fetch floor 576 MB/pass; WRITE now clean.
//   absmax 0.0625 (2 fp16 quantizations) — precision budget CLOSED.
// R11 (this round; infra-retry, kernel unchanged): ELIMINATE k1's gather via
// exact stats algebra.
//   Sum_y  = Sum_j c_j u[j]  - K * Sum_n v[n]
//   Sum_y2 = Sum_j c_j u[j]^2 - 2 Sum_j u[j]·(Wx·q[j]) + K Sum_n v[n]^2
//   where c_j = multiplicity of j in index, q[j] = Sum_{(n,k):idx=j} p[n].
//   k1a: scatter-add (p,1) into 16 MB qc table (36M fp32 atomics) + P1/P2
//        reduction. Reads index 36 + points 12 MB.
//   k1b: STREAMING pass over u+qc (80 MB): A_o = Sum c u, B_o = Sum c u^2,
//        C_o = Sum u·(Wx·q) — 60 accumulators, proven k1 grid-stride shape.
//   k3 preamble assembles mean/var in fp64 — algebraically identical stats.
//   Predict: k1 ~175 -> k1a 60-110 + k1b ~25; total 949 -> ~860-900.
//   Falsifier: k1a > 150 us, low BW, low VALU -> atomic-bound -> revert.
// Register discipline: (256,3) on gather/stride kernels; streaming matmuls
// plain (256); no array-ref helpers; all array indices compile-time.

constexpr int KNN_ = 9;
constexpr int CI   = 20;
constexpr int CC   = 23;
constexpr int CAT  = 40;
constexpr int USH  = 32;   // fp16 row stride in halves (64 B slot)
constexpr float EPS = 1e-5f;

template <int CNT>
__device__ __forceinline__ void block_reduce_add(float (&v)[CNT], double* __restrict__ dst,
                                                 float* __restrict__ lds /*4*CNT floats*/) {
    const int lane = threadIdx.x & 63;
    const int wid  = threadIdx.x >> 6;
#pragma unroll
    for (int i = 0; i < CNT; ++i) {
        float x = v[i];
#pragma unroll
        for (int off = 32; off > 0; off >>= 1) x += __shfl_down(x, off);
        if (lane == 0) lds[wid * CNT + i] = x;
    }
    __syncthreads();
    if (threadIdx.x < CNT) {
        float x = lds[threadIdx.x] + lds[CNT + threadIdx.x] +
                  lds[2 * CNT + threadIdx.x] + lds[3 * CNT + threadIdx.x];
        atomicAdd(dst + threadIdx.x, (double)x);
    }
}

__device__ __forceinline__ void loadrow20(const float* __restrict__ p, float (&v)[CI]) {
    const float4* q = reinterpret_cast<const float4*>(p);
    const float4 a = q[0], b = q[1], c = q[2], d = q[3], e = q[4];
    v[0]=a.x; v[1]=a.y; v[2]=a.z; v[3]=a.w;
    v[4]=b.x; v[5]=b.y; v[6]=b.z; v[7]=b.w;
    v[8]=c.x; v[9]=c.y; v[10]=c.z; v[11]=c.w;
    v[12]=d.x; v[13]=d.y; v[14]=d.z; v[15]=d.w;
    v[16]=e.x; v[17]=e.y; v[18]=e.z; v[19]=e.w;
}

__device__ __forceinline__ void storerow20(float* __restrict__ p, const float (&v)[CI]) {
    float4* q = reinterpret_cast<float4*>(p);
    q[0] = make_float4(v[0],  v[1],  v[2],  v[3]);
    q[1] = make_float4(v[4],  v[5],  v[6],  v[7]);
    q[2] = make_float4(v[8],  v[9],  v[10], v[11]);
    q[3] = make_float4(v[12], v[13], v[14], v[15]);
    q[4] = make_float4(v[16], v[17], v[18], v[19]);
}

__device__ __forceinline__ float2 h2f(unsigned int u) {
    return __half22float2(__builtin_bit_cast(__half2, u));
}

// fp16 row: 20 halves (40 B) at a 64-B-aligned slot. 3 vector loads.
__device__ __forceinline__ void loadrow20h(const __half* __restrict__ p, float (&v)[CI]) {
    const uint4 A = reinterpret_cast<const uint4*>(p)[0];   // halves 0..7
    const uint4 B = reinterpret_cast<const uint4*>(p)[1];   // halves 8..15
    const uint2 C = reinterpret_cast<const uint2*>(p)[4];   // halves 16..19
    float2 f;
    f = h2f(A.x); v[0]=f.x;  v[1]=f.y;
    f = h2f(A.y); v[2]=f.x;  v[3]=f.y;
    f = h2f(A.z); v[4]=f.x;  v[5]=f.y;
    f = h2f(A.w); v[6]=f.x;  v[7]=f.y;
    f = h2f(B.x); v[8]=f.x;  v[9]=f.y;
    f = h2f(B.y); v[10]=f.x; v[11]=f.y;
    f = h2f(B.z); v[12]=f.x; v[13]=f.y;
    f = h2f(B.w); v[14]=f.x; v[15]=f.y;
    f = h2f(C.x); v[16]=f.x; v[17]=f.y;
    f = h2f(C.y); v[18]=f.x; v[19]=f.y;
}

__device__ __forceinline__ unsigned int f2h(float a, float b) {
    return __builtin_bit_cast(unsigned int, __float22half2_rn(make_float2(a, b)));
}

// store 20 floats as fp16 + zero-pad to the full 64-B slot (full coverage,
// no read-for-ownership, one clean 64-B writeback).
__device__ __forceinline__ void storerow20h(__half* __restrict__ p, const float (&v)[CI]) {
    uint4* q = reinterpret_cast<uint4*>(p);
    q[0] = make_uint4(f2h(v[0],v[1]),   f2h(v[2],v[3]),   f2h(v[4],v[5]),   f2h(v[6],v[7]));
    q[1] = make_uint4(f2h(v[8],v[9]),   f2h(v[10],v[11]), f2h(v[12],v[13]), f2h(v[14],v[15]));
    q[2] = make_uint4(f2h(v[16],v[17]), f2h(v[18],v[19]), 0u, 0u);
    q[3] = make_uint4(0u, 0u, 0u, 0u);
}

// ---- K0: u[n] = W_f·feat[n] + W_x·p[n] (streamed, once; fp16 out) ----
__global__ __launch_bounds__(256) void k0_uv(
    const float* __restrict__ points, const float* __restrict__ feature,
    const float* __restrict__ W1, __half* __restrict__ u, int N)
{
    __shared__ float Ws[CI * CC];
    for (int i = threadIdx.x; i < CI * CC; i += 256) Ws[i] = W1[i];
    __syncthreads();
    const int n = blockIdx.x * 256 + threadIdx.x;
    if (n >= N) return;
    float in[CI];
    loadrow20(feature + (size_t)n * CI, in);
    const float px = points[3*n], py = points[3*n+1], pz = points[3*n+2];
    float uo[CI];
#pragma unroll
    for (int o = 0; o < CI; ++o) {
        float y = Ws[o*CC+20] * px;
        y = fmaf(Ws[o*CC+21], py, y);
        y = fmaf(Ws[o*CC+22], pz, y);
#pragma unroll
        for (int c = 0; c < CI; ++c) y = fmaf(Ws[o*CC+c], in[c], y);
        uo[o] = y;
    }
    storerow20h(u + (size_t)n * USH, uo);
}

// ---- K1a: scatter (p,1) into qc[j] for each (n,k); P1/P2 reduction ----
// qc[j] = (qx,qy,qz,c): q = sum of p[n] over occurrences of j, c = count.
// stats+60: P1 (3), P2 (6: xx,xy,xz,yy,yz,zz).
__global__ __launch_bounds__(256, 3) void k1a_scatter(
    const float* __restrict__ points, const int* __restrict__ index,
    float* __restrict__ qc, double* __restrict__ stats, int N)
{
    __shared__ float red[4 * 9];
    float accP[9];
#pragma unroll
    for (int i = 0; i < 9; ++i) accP[i] = 0.f;

#pragma unroll 1
    for (int n = blockIdx.x * 256 + threadIdx.x; n < N; n += gridDim.x * 256) {
        const float px = points[3*n], py = points[3*n+1], pz = points[3*n+2];
        accP[0] += px; accP[1] += py; accP[2] += pz;
        accP[3] = fmaf(px, px, accP[3]);
        accP[4] = fmaf(px, py, accP[4]);
        accP[5] = fmaf(px, pz, accP[5]);
        accP[6] = fmaf(py, py, accP[6]);
        accP[7] = fmaf(py, pz, accP[7]);
        accP[8] = fmaf(pz, pz, accP[8]);
        int idx[KNN_];
#pragma unroll
        for (int k = 0; k < KNN_; ++k) idx[k] = index[n * KNN_ + k];
#pragma unroll
        for (int k = 0; k < KNN_; ++k) {
            float* qj = qc + 4 * (size_t)idx[k];
            atomicAdd(qj + 0, px);
            atomicAdd(qj + 1, py);
            atomicAdd(qj + 2, pz);
            atomicAdd(qj + 3, 1.0f);
        }
    }
    __syncthreads();
    block_reduce_add<9>(accP, stats + 60, red);
}

// ---- K1b: streaming reduce over u + qc ----
// A_o = sum c_j u[j,o]; B_o = sum c_j u[j,o]^2; C_o = sum u[j,o]*(Wx[o]·q_j)
// into stats[0..60). Proven grid-stride accumulate shape (k1 lineage).
__global__ __launch_bounds__(256, 3) void k1b_reduce(
    const __half* __restrict__ u, const float* __restrict__ qc,
    const float* __restrict__ W1, double* __restrict__ stats, int N)
{
    __shared__ float Ws[CI * CC];
    __shared__ float red[4 * 3 * CI];
    for (int i = threadIdx.x; i < CI * CC; i += 256) Ws[i] = W1[i];
    __syncthreads();

    float acc[3 * CI];
#pragma unroll
    for (int i = 0; i < 3 * CI; ++i) acc[i] = 0.f;

#pragma unroll 1
    for (int n = blockIdx.x * 256 + threadIdx.x; n < N; n += gridDim.x * 256) {
        float uo[CI];
        loadrow20h(u + (size_t)n * USH, uo);
        const float4 q = reinterpret_cast<const float4*>(qc)[n];
#pragma unroll
        for (int o = 0; o < CI; ++o) {
            const float cu = q.w * uo[o];
            acc[o] += cu;
            acc[CI + o] = fmaf(cu, uo[o], acc[CI + o]);
            float r = Ws[o*CC+20] * q.x;
            r = fmaf(Ws[o*CC+21], q.y, r);
            r = fmaf(Ws[o*CC+22], q.z, r);
            acc[2*CI + o] = fmaf(uo[o], r, acc[2*CI + o]);
        }
    }
    __syncthreads();
    block_reduce_add<3 * CI>(acc, stats, red);
}

// ---- K3: xk = u[j]*sc - v2[n]; w_k = xk·x0; xagg = Σ xk w_k (fp16 out) ----
// R11: preamble assembles BN1 mean/var from A,B,C,P1,P2 in fp64.
__global__ __launch_bounds__(256, 3) void k3_attn(
    const float* __restrict__ points, const int* __restrict__ index,
    const float* __restrict__ W1, const float* __restrict__ g1,
    const float* __restrict__ b1, const double* __restrict__ stats,
    const __half* __restrict__ u,
    float* __restrict__ wbuf, __half* __restrict__ xagg, int N)
{
    __shared__ float Ws[CI * CC];
    __shared__ float sc[CI], sh[CI];
    for (int i = threadIdx.x; i < CI * CC; i += 256) Ws[i] = W1[i];
    if (threadIdx.x < CI) {
        const int o = threadIdx.x;
        const double A = stats[o], B = stats[CI + o], C = stats[2*CI + o];
        const double P1x = stats[60], P1y = stats[61], P1z = stats[62];
        const double xx = stats[63], xy = stats[64], xz = stats[65];
        const double yy = stats[66], yz = stats[67], zz = stats[68];
        const double w0 = W1[o*CC+20], w1 = W1[o*CC+21], w2 = W1[o*CC+22];
        const double Sv  = w0*P1x + w1*P1y + w2*P1z;
        const double Svv = w0*w0*xx + w1*w1*yy + w2*w2*zz
                         + 2.0*(w0*w1*xy + w0*w2*xz + w1*w2*yz);
        const double M9 = (double)N * KNN_;
        const double mean = (A - (double)KNN_ * Sv) / M9;
        const double Ey2  = (B - 2.0*C + (double)KNN_ * Svv) / M9;
        const double var  = Ey2 - mean * mean;
        const float s = g1[o] * rsqrtf((float)var + EPS);
        sc[o] = s;
        sh[o] = b1[o] - (float)mean * s;
    }
    __syncthreads();

    const int n = blockIdx.x * 256 + threadIdx.x;
    if (n >= N) return;

    const float px = points[3*n], py = points[3*n+1], pz = points[3*n+2];
    float v2[CI];   // v*sc - sh, so xk = u*sc - v2
#pragma unroll
    for (int o = 0; o < CI; ++o) {
        float t = Ws[o*CC+20] * px;
        t = fmaf(Ws[o*CC+21], py, t);
        t = fmaf(Ws[o*CC+22], pz, t);
        v2[o] = fmaf(t, sc[o], -sh[o]);
    }
    int idx[KNN_];
#pragma unroll
    for (int k = 0; k < KNN_; ++k) idx[k] = index[n * KNN_ + k];

    float x0[CI], accv[CI];
    {   // k = 0
        float r[CI];
        loadrow20h(u + (size_t)idx[0] * USH, r);
        float w0 = 0.f;
#pragma unroll
        for (int o = 0; o < CI; ++o) x0[o] = fmaf(r[o], sc[o], -v2[o]);
#pragma unroll
        for (int o = 0; o < CI; ++o) w0 = fmaf(x0[o], x0[o], w0);
        wbuf[n * KNN_] = w0;
#pragma unroll
        for (int o = 0; o < CI; ++o) accv[o] = x0[o] * w0;
    }
#pragma unroll 1
    for (int t = 0; t < 4; ++t) {
        const int ka = 1 + 2*t, kb = 2 + 2*t;
        float ra[CI], rb[CI];
        loadrow20h(u + (size_t)idx[ka] * USH, ra);
        loadrow20h(u + (size_t)idx[kb] * USH, rb);
        float wa = 0.f, wb = 0.f;
#pragma unroll
        for (int o = 0; o < CI; ++o) {
            ra[o] = fmaf(ra[o], sc[o], -v2[o]);
            wa = fmaf(ra[o], x0[o], wa);
        }
#pragma unroll
        for (int o = 0; o < CI; ++o) {
            rb[o] = fmaf(rb[o], sc[o], -v2[o]);
            wb = fmaf(rb[o], x0[o], wb);
        }
        wbuf[n * KNN_ + ka] = wa;
        wbuf[n * KNN_ + kb] = wb;
#pragma unroll
        for (int o = 0; o < CI; ++o) accv[o] = fmaf(ra[o], wa, accv[o]);
#pragma unroll
        for (int o = 0; o < CI; ++o) accv[o] = fmaf(rb[o], wb, accv[o]);
    }
    storerow20h(xagg + (size_t)n * USH, accv);
}

// ---- K4: x2[n] = Σ_k xagg[idx[n,k]]·w[n,k]; fused BN2 stats ----
__global__ __launch_bounds__(256, 3) void k4_prop(
    const int* __restrict__ index, const float* __restrict__ wbuf,
    const __half* __restrict__ xagg, float* __restrict__ x2,
    double* __restrict__ stats2, int N)
{
    __shared__ float red[4 * 2 * CI];
    float st[2 * CI];
#pragma unroll
    for (int i = 0; i < 2 * CI; ++i) st[i] = 0.f;

#pragma unroll 1
    for (int n = blockIdx.x * 256 + threadIdx.x; n < N; n += gridDim.x * 256) {
        int idx[KNN_];
        float wk[KNN_];
#pragma unroll
        for (int k = 0; k < KNN_; ++k) idx[k] = index[n * KNN_ + k];
#pragma unroll
        for (int k = 0; k < KNN_; ++k) wk[k] = wbuf[n * KNN_ + k];

        float accv[CI];
        {
            float r[CI];
            loadrow20h(xagg + (size_t)idx[0] * USH, r);
#pragma unroll
            for (int o = 0; o < CI; ++o) accv[o] = r[o] * wk[0];
        }
#pragma unroll 1
        for (int t = 0; t < 4; ++t) {
            const int ka = 1 + 2*t, kb = 2 + 2*t;
            float ra[CI], rb[CI];
            loadrow20h(xagg + (size_t)idx[ka] * USH, ra);
            loadrow20h(xagg + (size_t)idx[kb] * USH, rb);
#pragma unroll
            for (int o = 0; o < CI; ++o) accv[o] = fmaf(ra[o], wk[ka], accv[o]);
#pragma unroll
            for (int o = 0; o < CI; ++o) accv[o] = fmaf(rb[o], wk[kb], accv[o]);
        }
        storerow20(x2 + (size_t)n * CI, accv);
#pragma unroll
        for (int o = 0; o < CI; ++o) {
            st[o] += accv[o];
            st[CI + o] = fmaf(accv[o], accv[o], st[CI + o]);
        }
    }
    __syncthreads();
    block_reduce_add<2 * CI>(st, stats2, red);
}

// ---- K6: h=relu(bn2(x2)); ybuf = Wr1@[h,feature]+br1 ----
// R7: k0's proven shape — plain (256), one point/thread, two 20x20 dot
// halves sharing in[20]. Live ~50 floats, no arrays with >1-iter liveness.
__global__ __launch_bounds__(256) void k6_refine1(
    const float* __restrict__ x2, const float* __restrict__ feature,
    const float* __restrict__ g2, const float* __restrict__ b2,
    const float* __restrict__ Wr1, const float* __restrict__ br1,
    const double* __restrict__ stats2,
    float* __restrict__ ybuf, int N)
{
    __shared__ float Ws[CI * CAT];
    __shared__ float sc[CI], sh[CI], brs[CI];
    for (int i = threadIdx.x; i < CI * CAT; i += 256) Ws[i] = Wr1[i];
    if (threadIdx.x < CI) {
        const double M = (double)N;
        const double mean = stats2[threadIdx.x] / M;
        const double var  = stats2[CI + threadIdx.x] / M - mean * mean;
        const float s = g2[threadIdx.x] * rsqrtf((float)var + EPS);
        sc[threadIdx.x] = s;
        sh[threadIdx.x] = b2[threadIdx.x] - (float)mean * s;
        brs[threadIdx.x] = br1[threadIdx.x];
    }
    __syncthreads();

    const int n = blockIdx.x * 256 + threadIdx.x;
    if (n >= N) return;

    float in[CI];
    // phase 1: h = relu(bn2(x2)); yv = br1 + W[:,0:20]·h
    loadrow20(x2 + (size_t)n * CI, in);
#pragma unroll
    for (int o = 0; o < CI; ++o)
        in[o] = fmaxf(fmaf(in[o], sc[o], sh[o]), 0.f);
    float yv[CI];
#pragma unroll
    for (int o = 0; o < CI; ++o) {
        float y = brs[o];
#pragma unroll
        for (int c = 0; c < CI; ++c) y = fmaf(Ws[o * CAT + c], in[c], y);
        yv[o] = y;
    }
    // phase 2: yv += W[:,20:40]·feature
    loadrow20(feature + (size_t)n * CI, in);
#pragma unroll
    for (int o = 0; o < CI; ++o) {
        float y = yv[o];
#pragma unroll
        for (int c = 0; c < CI; ++c) y = fmaf(Ws[o * CAT + CI + c], in[c], y);
        yv[o] = y;
    }
    storerow20(ybuf + (size_t)n * CI, yv);
}

// ---- K7: BN3 stats over ybuf (pure streaming, 80 MB) ----
__global__ __launch_bounds__(256) void k7_stats3(
    const float* __restrict__ ybuf, double* __restrict__ stats3, int N)
{
    __shared__ float red[4 * 2 * CI];
    float st[2 * CI];
#pragma unroll
    for (int i = 0; i < 2 * CI; ++i) st[i] = 0.f;

#pragma unroll 1
    for (int n = blockIdx.x * 256 + threadIdx.x; n < N; n += gridDim.x * 256) {
        float yv[CI];
        loadrow20(ybuf + (size_t)n * CI, yv);
#pragma unroll
        for (int o = 0; o < CI; ++o) {
            st[o] += yv[o];
            st[CI + o] = fmaf(yv[o], yv[o], st[CI + o]);
        }
    }
    __syncthreads();
    block_reduce_add<2 * CI>(st, stats3, red);
}

// ---- K8: out = relu(bn3(y)) @ Wr2.T + br2 ----
__global__ __launch_bounds__(256) void k8_out(
    const float* __restrict__ ybuf,
    const float* __restrict__ g3, const float* __restrict__ b3,
    const float* __restrict__ Wr2, const float* __restrict__ br2,
    const double* __restrict__ stats3, float* __restrict__ out, int N)
{
    __shared__ float Ws[CI * CI];
    __shared__ float sc[CI], sh[CI];
    for (int i = threadIdx.x; i < CI * CI; i += 256) Ws[i] = Wr2[i];
    if (threadIdx.x < CI) {
        const double M = (double)N;
        const double mean = stats3[threadIdx.x] / M;
        const double var  = stats3[CI + threadIdx.x] / M - mean * mean;
        const float s = g3[threadIdx.x] * rsqrtf((float)var + EPS);
        sc[threadIdx.x] = s;
        sh[threadIdx.x] = b3[threadIdx.x] - (float)mean * s;
    }
    __syncthreads();

    const int n = blockIdx.x * 256 + threadIdx.x;
    if (n >= N) return;

    float z[CI];
    {
        float yi[CI];
        loadrow20(ybuf + (size_t)n * CI, yi);
#pragma unroll
        for (int o = 0; o < CI; ++o)
            z[o] = fmaxf(fmaf(yi[o], sc[o], sh[o]), 0.f);
    }
    float ov[CI];
#pragma unroll
    for (int o = 0; o < CI; ++o) {
        float y = br2[o];
#pragma unroll
        for (int c = 0; c < CI; ++c) y = fmaf(Ws[o * CI + c], z[c], y);
        ov[o] = y;
    }
    storerow20(out + (size_t)n * CI, ov);
}

extern "C" void kernel_launch(void* const* d_in, const int* in_sizes, int n_in,
                              void* d_out, int out_size, void* d_ws, size_t ws_size,
                              hipStream_t stream) {
    const float* points  = (const float*)d_in[0];
    const float* feature = (const float*)d_in[1];
    const int*   index   = (const int*)  d_in[2];
    const float* W1      = (const float*)d_in[3];
    const float* g1      = (const float*)d_in[4];
    const float* b1      = (const float*)d_in[5];
    const float* g2      = (const float*)d_in[6];
    const float* b2      = (const float*)d_in[7];
    const float* Wr1     = (const float*)d_in[8];
    const float* br1     = (const float*)d_in[9];
    const float* g3      = (const float*)d_in[10];
    const float* b3      = (const float*)d_in[11];
    const float* Wr2     = (const float*)d_in[12];
    const float* br2     = (const float*)d_in[13];
    const int N = in_sizes[0] / 3;
    float* out = (float*)d_out;

    // ws layout:
    //   [stats 2KB: 0..20 A | 20..40 B | 40..60 C | 60..69 P1,P2 |
    //    80..120 stats2 | 120..160 stats3]
    //   [wbuf N*9 f32 = 36MB]
    //   [region A 80MB: u fp16 (64MB used) -> x2 f32 (80MB) after k3]
    //   [region B 80MB: xagg fp16 (64MB used) -> ybuf f32 (80MB) after k4]
    //   [qc N*4 f32 = 16MB  (q scatter table; zeroed each launch)]
    // Total = 2KB + 36 + 80 + 80 + 16 = 212 MB.
    double* stats = (double*)d_ws;
    char* base = (char*)d_ws;
    size_t off = 2048;
    float*  wbuf = (float*)(base + off); off += (size_t)N * KNN_ * 4;
    __half* u    = (__half*)(base + off);
    float*  x2   = (float*)(base + off); off += (size_t)N * CI * 4;  // 80 MB region
    __half* xagg = (__half*)(base + off);
    float*  ybuf = (float*)(base + off); off += (size_t)N * CI * 4;  // 80 MB region
    float*  qc   = (float*)(base + off);

    hipMemsetAsync(stats, 0, 160 * sizeof(double), stream);
    hipMemsetAsync(qc, 0, (size_t)N * 4 * sizeof(float), stream);

    const int B = 256;
    const int gridN = (N + B - 1) / B;
    k0_uv      <<<gridN, B, 0, stream>>>(points, feature, W1, u, N);
    k1a_scatter<<<2048, B, 0, stream>>>(points, index, qc, stats, N);
    k1b_reduce <<<2048, B, 0, stream>>>(u, qc, W1, stats, N);
    k3_attn    <<<gridN, B, 0, stream>>>(points, index, W1, g1, b1, stats, u, wbuf, xagg, N);
    k4_prop    <<<2048, B, 0, stream>>>(index, wbuf, xagg, x2, stats + 80, N);
    k6_refine1 <<<gridN, B, 0, stream>>>(x2, feature, g2, b2, Wr1, br1, stats + 80, ybuf, N);
    k7_stats3  <<<2048, B, 0, stream>>>(ybuf, stats + 120, N);
    k8_out     <<<gridN, B, 0, stream>>>(ybuf, g3, b3, Wr2, br2, stats + 120, out, N);
}